// Round 6
// baseline (5683.121 us; speedup 1.0000x reference)
//
#include <hip/hip_runtime.h>

// Problem constants
#define TSEQ 512
#define NB   32     // batch
#define DB   768    // d_bert
#define H2E  128    // encoder hidden per dir
#define DL   256    // d_lstm
#define NC   16     // n_class

typedef unsigned long long ull;
typedef float f32x4 __attribute__((ext_vector_type(4)));

__device__ __forceinline__ float sigf(float x) { return 1.0f / (1.0f + __expf(-x)); }
__device__ __forceinline__ float tanhfast(float x) { return 1.0f - 2.0f / (1.0f + __expf(2.0f * x)); }

// ---------------------------------------------------------------------------
// Generic f32 GEMM: C[remap(m), n] = sum_k A[m,k]*W[n,k] + b1[n] + b2[n]
// 64x64 tile, BK=16, 256 threads, 4x4 microtile.
// MODE 0: direct rows. MODE 1: m=b*T+t -> out row t*NB+b. MODE 2: -> (T-1-t)*NB+b.
// ---------------------------------------------------------------------------
template <int MODE>
__global__ __launch_bounds__(256) void gemm_nt(
    const float* __restrict__ A, int lda,
    const float* __restrict__ W, int ldw,
    const float* __restrict__ b1, const float* __restrict__ b2,
    float* __restrict__ C, int ldc, int N, int K)
{
    __shared__ float As[16][68];
    __shared__ float Ws[16][68];
    const int tid = threadIdx.x;
    const int m0 = blockIdx.x * 64;
    const int n0 = blockIdx.y * 64;
    const int tx = tid & 15, ty = tid >> 4;
    const int lrow = tid >> 2;
    const int lk = (tid & 3) * 4;
    float acc[4][4] = {};

    for (int k0 = 0; k0 < K; k0 += 16) {
        float4 av = *(const float4*)(A + (size_t)(m0 + lrow) * lda + k0 + lk);
        float4 wv = make_float4(0.f, 0.f, 0.f, 0.f);
        if (n0 + lrow < N)
            wv = *(const float4*)(W + (size_t)(n0 + lrow) * ldw + k0 + lk);
        As[lk + 0][lrow] = av.x; As[lk + 1][lrow] = av.y;
        As[lk + 2][lrow] = av.z; As[lk + 3][lrow] = av.w;
        Ws[lk + 0][lrow] = wv.x; Ws[lk + 1][lrow] = wv.y;
        Ws[lk + 2][lrow] = wv.z; Ws[lk + 3][lrow] = wv.w;
        __syncthreads();
#pragma unroll
        for (int kk = 0; kk < 16; ++kk) {
            float a0 = As[kk][ty * 4 + 0], a1 = As[kk][ty * 4 + 1];
            float a2 = As[kk][ty * 4 + 2], a3 = As[kk][ty * 4 + 3];
            float w0 = Ws[kk][tx * 4 + 0], w1 = Ws[kk][tx * 4 + 1];
            float w2 = Ws[kk][tx * 4 + 2], w3 = Ws[kk][tx * 4 + 3];
            acc[0][0] += a0 * w0; acc[0][1] += a0 * w1; acc[0][2] += a0 * w2; acc[0][3] += a0 * w3;
            acc[1][0] += a1 * w0; acc[1][1] += a1 * w1; acc[1][2] += a1 * w2; acc[1][3] += a1 * w3;
            acc[2][0] += a2 * w0; acc[2][1] += a2 * w1; acc[2][2] += a2 * w2; acc[2][3] += a2 * w3;
            acc[3][0] += a3 * w0; acc[3][1] += a3 * w1; acc[3][2] += a3 * w2; acc[3][3] += a3 * w3;
        }
        __syncthreads();
    }

#pragma unroll
    for (int i = 0; i < 4; ++i) {
        int gm = m0 + ty * 4 + i;
        int orow;
        if (MODE == 0) orow = gm;
        else {
            int bb = gm >> 9;          // /TSEQ
            int tt = gm & (TSEQ - 1);
            orow = (MODE == 1 ? tt : (TSEQ - 1 - tt)) * NB + bb;
        }
#pragma unroll
        for (int j = 0; j < 4; ++j) {
            int gn = n0 + tx * 4 + j;
            if (gn < N) {
                float bias = (b1 ? b1[gn] : 0.f) + (b2 ? b2[gn] : 0.f);
                C[(size_t)orow * ldc + gn] = acc[i][j] + bias;
            }
        }
    }
}

// ---------------------------------------------------------------------------
// Encoder LSTM scan (unchanged).
// ---------------------------------------------------------------------------
__global__ __launch_bounds__(512) void enc_scan(
    const float* __restrict__ Gf, const float* __restrict__ Gr,
    const float* __restrict__ Whh_f, const float* __restrict__ Whh_r,
    float* __restrict__ hs_ctx)
{
    const int dir = blockIdx.x & 1;
    const int b = blockIdx.x >> 1;
    const float* __restrict__ G = dir ? Gr : Gf;
    const float* __restrict__ Whh = dir ? Whh_r : Whh_f;
    const int j = threadIdx.x;   // gate 0..511

    __shared__ float4 h4[H2E / 4];
    __shared__ float gates[4 * H2E];
    float* h_s = (float*)h4;

    float4 w[32];
#pragma unroll
    for (int k = 0; k < 32; ++k)
        w[k] = *(const float4*)(Whh + (size_t)j * H2E + k * 4);

    float c = 0.f;
    if (j < H2E) h_s[j] = 0.f;
    __syncthreads();

    for (int t = 0; t < TSEQ; ++t) {
        const float* grow = G + ((size_t)t * NB + b) * 512;
        float acc = grow[j];
#pragma unroll
        for (int k = 0; k < 32; ++k) {
            float4 hv = h4[k];
            acc += w[k].x * hv.x + w[k].y * hv.y + w[k].z * hv.z + w[k].w * hv.w;
        }
        gates[j] = acc;
        __syncthreads();
        if (j < H2E) {
            float ig = sigf(gates[j]);
            float fg = sigf(gates[j + H2E]);
            float gg = tanhfast(gates[j + 2 * H2E]);
            float og = sigf(gates[j + 3 * H2E]);
            c = fg * c + ig * gg;
            float h = og * tanhfast(c);
            h_s[j] = h;
            int tout = dir ? (TSEQ - 1 - t) : t;
            hs_ctx[((size_t)b * TSEQ + tout) * 512 + dir * H2E + j] = h;
        }
        __syncthreads();
    }
}

// ---------------------------------------------------------------------------
// Fused additive-attention scores + softmax (unchanged).
// ---------------------------------------------------------------------------
__global__ __launch_bounds__(256) void attn_w(
    const float* __restrict__ qp, const float* __restrict__ kp,
    const int* __restrict__ mask, const float* __restrict__ fc2,
    float* __restrict__ wout)
{
    const int bi = blockIdx.x;       // b*T + i
    const int b = bi >> 9;
    const int tid = threadIdx.x;
    __shared__ float kps[TSEQ * 11];
    __shared__ float red[8];

    const float* kpb = kp + (size_t)b * TSEQ * 10;
    for (int idx = tid; idx < TSEQ * 10; idx += 256) {
        int j = idx / 10, xx = idx - j * 10;
        kps[j * 11 + xx] = kpb[idx];
    }
    float q[10], vv[10];
#pragma unroll
    for (int xx = 0; xx < 10; ++xx) {
        q[xx] = qp[(size_t)bi * 10 + xx];
        vv[xx] = fc2[xx];
    }
    __syncthreads();

    float a[2];
#pragma unroll
    for (int jj = 0; jj < 2; ++jj) {
        int j = tid + jj * 256;
        float s = 0.f;
#pragma unroll
        for (int xx = 0; xx < 10; ++xx)
            s += vv[xx] * tanhfast(q[xx] + kps[j * 11 + xx]);
        if (mask[(size_t)b * TSEQ + j] == 0) s = -1e30f;
        a[jj] = s;
    }

    float m = fmaxf(a[0], a[1]);
#pragma unroll
    for (int o = 32; o >= 1; o >>= 1) m = fmaxf(m, __shfl_xor(m, o));
    if ((tid & 63) == 0) red[tid >> 6] = m;
    __syncthreads();
    m = fmaxf(fmaxf(red[0], red[1]), fmaxf(red[2], red[3]));

    float e0 = __expf(a[0] - m), e1 = __expf(a[1] - m);
    float s = e0 + e1;
#pragma unroll
    for (int o = 32; o >= 1; o >>= 1) s += __shfl_xor(s, o);
    if ((tid & 63) == 0) red[4 + (tid >> 6)] = s;
    __syncthreads();
    s = (red[4] + red[5]) + (red[6] + red[7]);
    float inv = 1.0f / s;
    wout[(size_t)bi * TSEQ + tid] = e0 * inv;
    wout[(size_t)bi * TSEQ + tid + 256] = e1 * inv;
}

// ---------------------------------------------------------------------------
// Batched NN GEMM: ctx = w @ hs (unchanged).
// ---------------------------------------------------------------------------
__global__ __launch_bounds__(256) void bgemm_nn(
    const float* __restrict__ Wmat,  // (NB, T, T)
    float* __restrict__ hs_ctx)      // (NB*T, 512): read cols [0,256), write [256,512)
{
    __shared__ float As[16][68];
    __shared__ float Bs[16][68];
    const int tid = threadIdx.x;
    const int b = blockIdx.z;
    const int i0 = blockIdx.x * 64;
    const int d0 = blockIdx.y * 64;
    const int tx = tid & 15, ty = tid >> 4;
    float acc[4][4] = {};
    const float* Ab = Wmat + (size_t)b * TSEQ * TSEQ;
    const float* Bb = hs_ctx + (size_t)b * TSEQ * 512;

    for (int k0 = 0; k0 < TSEQ; k0 += 16) {
        {
            int r = tid >> 2, kq = (tid & 3) * 4;
            float4 v = *(const float4*)(Ab + (size_t)(i0 + r) * TSEQ + k0 + kq);
            As[kq + 0][r] = v.x; As[kq + 1][r] = v.y; As[kq + 2][r] = v.z; As[kq + 3][r] = v.w;
        }
        {
            int kk = tid >> 4, dq = (tid & 15) * 4;
            float4 v = *(const float4*)(Bb + (size_t)(k0 + kk) * 512 + d0 + dq);
            *(float4*)&Bs[kk][dq] = v;
        }
        __syncthreads();
#pragma unroll
        for (int kk = 0; kk < 16; ++kk) {
            float a0 = As[kk][ty * 4 + 0], a1 = As[kk][ty * 4 + 1];
            float a2 = As[kk][ty * 4 + 2], a3 = As[kk][ty * 4 + 3];
            float b0 = Bs[kk][tx * 4 + 0], b1 = Bs[kk][tx * 4 + 1];
            float b2 = Bs[kk][tx * 4 + 2], b3 = Bs[kk][tx * 4 + 3];
            acc[0][0] += a0 * b0; acc[0][1] += a0 * b1; acc[0][2] += a0 * b2; acc[0][3] += a0 * b3;
            acc[1][0] += a1 * b0; acc[1][1] += a1 * b1; acc[1][2] += a1 * b2; acc[1][3] += a1 * b3;
            acc[2][0] += a2 * b0; acc[2][1] += a2 * b1; acc[2][2] += a2 * b2; acc[2][3] += a2 * b3;
            acc[3][0] += a3 * b0; acc[3][1] += a3 * b1; acc[3][2] += a3 * b2; acc[3][3] += a3 * b3;
        }
        __syncthreads();
    }
#pragma unroll
    for (int i = 0; i < 4; ++i)
#pragma unroll
        for (int j = 0; j < 4; ++j)
            hs_ctx[((size_t)b * TSEQ + i0 + ty * 4 + i) * 512 + 256 + d0 + tx * 4 + j] = acc[i][j];
}

// ---------------------------------------------------------------------------
// Decoder init v4: clear ALL tags in hbuf/lbuf (both parities), then write
// h(-1) (tag=1) into hbuf parity 0. Runs every launch (replay-safe).
// hbuf/lbuf words: (tag << 32) | f32 bits.
// ---------------------------------------------------------------------------
__global__ __launch_bounds__(256) void dec_init4(
    const float* __restrict__ hs_ctx, ull* hbuf, ull* lbuf)
{
    const int gid = blockIdx.x * 256 + threadIdx.x;
    for (int idx = gid; idx < 32768; idx += 16 * 256) {
        ull v = 0ull;
        if (idx < 8192) {            // hbuf parity 0: h(-1) with tag 1
            int b = idx >> 8, u = idx & 255;
            float hv = hs_ctx[((size_t)b * TSEQ + (TSEQ - 1)) * 512 + u];
            v = (1ull << 32) | (ull)__float_as_uint(hv);
        }
        ull* dst = (idx < 16384) ? (hbuf + idx) : (lbuf + (idx - 16384));
        __hip_atomic_store(dst, v, __ATOMIC_RELAXED, __HIP_MEMORY_SCOPE_AGENT);
    }
}

// ---------------------------------------------------------------------------
// Decoder scan v5: tag-carried sync + asm-pinned register weights.
// 128 blocks = 16 row-groups x 8 batch-groups; thread = (kseg=tid>>6, rr=tid&63).
// Published words pack (step-tag, value) in 8B -> readers poll the data itself
// (no flags, no vmcnt drain on the critical path). Weights pinned in VGPRs via
// opaque asm so the compiler cannot rematerialize the loads into the loop.
// h(t) -> hbuf[(t+1)&1], tag t+2. Reader at step t polls buf[t&1] for tag t+1.
// lbuf: per-rg partial logits, same tagging.
// ---------------------------------------------------------------------------
__global__ __launch_bounds__(256) void dec_scan4(
    const float* __restrict__ Gd,     // (T, NB, 1024), biases folded
    const float* __restrict__ Whh,    // (1024, 256)
    const float* __restrict__ Wih,    // (1024, 272); cols 256:272 multiply y
    const float* __restrict__ lin_w,  // (16, 256)
    const float* __restrict__ lin_b,  // (16,)
    ull* hbuf,                        // (2, NB, 256) tagged h
    ull* lbuf,                        // (2, NB, 256) tagged logit partials
    float* __restrict__ out)          // (NB, T, NC)
{
    const int tid = threadIdx.x;
    const int rg  = blockIdx.x & 15;
    const int bg  = blockIdx.x >> 4;
    const int kseg = tid >> 6;        // wave id 0..3 (wave-uniform)
    const int rr   = tid & 63;        // gate row 0..63 within block
    const int jrow = ((rr >> 4) << 8) + rg * 16 + (rr & 15);

    __shared__ float hlds[4][260];    // h(t-1) for 4 batches
    __shared__ float part[4][4][66];  // [bb][kseg][rr] gate partials
    __shared__ float ylds[4][16];     // y(t-1)
    __shared__ float hnew[4][16];     // this block's new h slice
    __shared__ float linl[16][17];    // lin_w[cls][rg*16+u]

    // ---- weights into registers, pinned against rematerialization ----
    f32x4 w[16];
    {
        const float* wrow = Whh + (size_t)jrow * 256 + kseg * 64;
#pragma unroll
        for (int i = 0; i < 16; ++i) w[i] = *(const f32x4*)(wrow + i * 4);
    }
#pragma unroll
    for (int i = 0; i < 16; ++i) asm volatile("" : "+v"(w[i]));
    f32x4 wy = *(const f32x4*)(Wih + (size_t)jrow * 272 + 256 + kseg * 4);
    asm volatile("" : "+v"(wy));

    linl[tid >> 4][tid & 15] = lin_w[(tid >> 4) * 256 + rg * 16 + (tid & 15)];
    const float lb = lin_b[tid & 15];
    const int ybb = tid >> 4, ycls = tid & 15;   // meaningful for tid<64

    float cstate = 0.f;               // live in tid<64: (bb=tid>>4, u=tid&15)
    __syncthreads();

    for (int t = 0; t <= TSEQ; ++t) {
        // prefetch Gd (independent of h); wave 0 only
        float gv0 = 0.f, gv1 = 0.f, gv2 = 0.f, gv3 = 0.f;
        if (kseg == 0 && t < TSEQ) {
            const float* gb = Gd + ((size_t)t * NB + bg * 4) * 1024 + jrow;
            gv0 = gb[0]; gv1 = gb[1024]; gv2 = gb[2048]; gv3 = gb[3072];
        }

        // ---- poll tagged data: h(t-1) (all threads) + logit partials (wave0) ----
        const unsigned want = (unsigned)(t + 1);
        const ull* hsrc = hbuf + (size_t)(t & 1) * (NB * 256) + (size_t)bg * 4 * 256;
        const ull* lsrc = lbuf + (size_t)(t & 1) * (NB * 256) + (size_t)bg * 4 * 256;
        const bool lneed = (tid < 64) && (t > 0);
        ull h0, h1, h2, h3;
        float lsum = 0.f;
        for (;;) {
            h0 = __hip_atomic_load(hsrc + tid,       __ATOMIC_RELAXED, __HIP_MEMORY_SCOPE_AGENT);
            h1 = __hip_atomic_load(hsrc + tid + 256, __ATOMIC_RELAXED, __HIP_MEMORY_SCOPE_AGENT);
            h2 = __hip_atomic_load(hsrc + tid + 512, __ATOMIC_RELAXED, __HIP_MEMORY_SCOPE_AGENT);
            h3 = __hip_atomic_load(hsrc + tid + 768, __ATOMIC_RELAXED, __HIP_MEMORY_SCOPE_AGENT);
            bool ok = ((unsigned)(h0 >> 32) == want) && ((unsigned)(h1 >> 32) == want)
                   && ((unsigned)(h2 >> 32) == want) && ((unsigned)(h3 >> 32) == want);
            if (lneed) {
                lsum = lb;
#pragma unroll
                for (int r = 0; r < 16; ++r) {
                    ull lv = __hip_atomic_load(lsrc + ybb * 256 + r * 16 + ycls,
                                               __ATOMIC_RELAXED, __HIP_MEMORY_SCOPE_AGENT);
                    ok &= ((unsigned)(lv >> 32) == want);
                    lsum += __uint_as_float((unsigned)lv);
                }
            }
            if (ok) break;
            __builtin_amdgcn_s_sleep(1);
        }
        hlds[0][tid] = __uint_as_float((unsigned)h0);
        hlds[1][tid] = __uint_as_float((unsigned)h1);
        hlds[2][tid] = __uint_as_float((unsigned)h2);
        hlds[3][tid] = __uint_as_float((unsigned)h3);
        __syncthreads();   // sync1: hlds ready

        // y(t-1): softmax over summed partials (wave0, 16-lane groups)
        if (tid < 64) {
            float yv = 0.f;
            if (t > 0) {
                float m = lsum;
#pragma unroll
                for (int o = 1; o < 16; o <<= 1) m = fmaxf(m, __shfl_xor(m, o, 16));
                float e = __expf(lsum - m);
                float ss = e;
#pragma unroll
                for (int o = 1; o < 16; o <<= 1) ss += __shfl_xor(ss, o, 16);
                yv = e / ss;
                if (rg == 0)
                    out[(((size_t)(bg * 4 + ybb)) * TSEQ + (t - 1)) * NC + ycls] = yv;
            }
            ylds[ybb][ycls] = yv;
        }
        __syncthreads();   // sync2: ylds ready

        if (t == TSEQ) break;   // uniform across block

        // ---- gate partials: weights from pinned regs, h via LDS broadcast ----
        {
            float a0, a1, a2, a3;
            a0 = wy.x * ylds[0][kseg * 4 + 0] + wy.y * ylds[0][kseg * 4 + 1]
               + wy.z * ylds[0][kseg * 4 + 2] + wy.w * ylds[0][kseg * 4 + 3];
            a1 = wy.x * ylds[1][kseg * 4 + 0] + wy.y * ylds[1][kseg * 4 + 1]
               + wy.z * ylds[1][kseg * 4 + 2] + wy.w * ylds[1][kseg * 4 + 3];
            a2 = wy.x * ylds[2][kseg * 4 + 0] + wy.y * ylds[2][kseg * 4 + 1]
               + wy.z * ylds[2][kseg * 4 + 2] + wy.w * ylds[2][kseg * 4 + 3];
            a3 = wy.x * ylds[3][kseg * 4 + 0] + wy.y * ylds[3][kseg * 4 + 1]
               + wy.z * ylds[3][kseg * 4 + 2] + wy.w * ylds[3][kseg * 4 + 3];
            if (kseg == 0) { a0 += gv0; a1 += gv1; a2 += gv2; a3 += gv3; }
#pragma unroll
            for (int i = 0; i < 16; ++i) {
                const f32x4 wv = w[i];
                const int kc = kseg * 64 + i * 4;
                f32x4 p0 = *(const f32x4*)&hlds[0][kc];
                f32x4 p1 = *(const f32x4*)&hlds[1][kc];
                f32x4 p2 = *(const f32x4*)&hlds[2][kc];
                f32x4 p3 = *(const f32x4*)&hlds[3][kc];
                a0 += wv.x * p0.x + wv.y * p0.y + wv.z * p0.z + wv.w * p0.w;
                a1 += wv.x * p1.x + wv.y * p1.y + wv.z * p1.z + wv.w * p1.w;
                a2 += wv.x * p2.x + wv.y * p2.y + wv.z * p2.z + wv.w * p2.w;
                a3 += wv.x * p3.x + wv.y * p3.y + wv.z * p3.z + wv.w * p3.w;
            }
            part[0][kseg][rr] = a0;
            part[1][kseg][rr] = a1;
            part[2][kseg][rr] = a2;
            part[3][kseg][rr] = a3;
        }
        __syncthreads();   // sync3: part ready

        // ---- finalize: reduce ksegs, nonlinearity, publish tagged words ----
        if (tid < 64) {
            const int bb = ybb, u = ycls;
            float gi = 0.f, gf = 0.f, gg = 0.f, go = 0.f;
#pragma unroll
            for (int ks = 0; ks < 4; ++ks) {
                gi += part[bb][ks][u];
                gf += part[bb][ks][u + 16];
                gg += part[bb][ks][u + 32];
                go += part[bb][ks][u + 48];
            }
            float ig = sigf(gi), fg = sigf(gf);
            float gvv = tanhfast(gg), og = sigf(go);
            cstate = fg * cstate + ig * gvv;
            float h = og * tanhfast(cstate);
            hnew[bb][u] = h;
            const ull tagbits = ((ull)(unsigned)(t + 2)) << 32;
            ull* hdst = hbuf + (size_t)((t + 1) & 1) * (NB * 256)
                      + (size_t)(bg * 4 + bb) * 256 + rg * 16 + u;
            __hip_atomic_store(hdst, tagbits | (ull)__float_as_uint(h),
                               __ATOMIC_RELAXED, __HIP_MEMORY_SCOPE_AGENT);
            // partial logit for (bb, cls=u) over this block's 16 h-units
            float lp = 0.f;
#pragma unroll
            for (int u2 = 0; u2 < 16; ++u2)
                lp += linl[u][u2] * hnew[bb][u2];
            ull* ldst = lbuf + (size_t)((t + 1) & 1) * (NB * 256)
                      + (size_t)(bg * 4 + bb) * 256 + rg * 16 + u;
            __hip_atomic_store(ldst, tagbits | (ull)__float_as_uint(lp),
                               __ATOMIC_RELAXED, __HIP_MEMORY_SCOPE_AGENT);
        }
        // no end barrier: next-step poll self-gates on our own publish
    }
}

// ---------------------------------------------------------------------------
extern "C" void kernel_launch(void* const* d_in, const int* in_sizes, int n_in,
                              void* d_out, int out_size, void* d_ws, size_t ws_size,
                              hipStream_t stream)
{
    const float* x     = (const float*)d_in[0];
    const int*   mask  = (const int*)d_in[1];
    const float* Wih_f = (const float*)d_in[2];
    const float* Whh_f = (const float*)d_in[3];
    const float* bih_f = (const float*)d_in[4];
    const float* bhh_f = (const float*)d_in[5];
    const float* Wih_r = (const float*)d_in[6];
    const float* Whh_r = (const float*)d_in[7];
    const float* bih_r = (const float*)d_in[8];
    const float* bhh_r = (const float*)d_in[9];
    const float* fc1_w = (const float*)d_in[10];
    const float* fc2_w = (const float*)d_in[11];
    const float* fc3_w = (const float*)d_in[12];
    const float* fc3_b = (const float*)d_in[13];
    const float* Wih_d = (const float*)d_in[14];
    const float* Whh_d = (const float*)d_in[15];
    const float* bih_d = (const float*)d_in[16];
    const float* bhh_d = (const float*)d_in[17];
    const float* lin_w = (const float*)d_in[18];
    const float* lin_b = (const float*)d_in[19];

    float* ws = (float*)d_ws;
    // layout (floats): Gf[8M] Gr[8M] hs[8M] wat[8M] qp[160K] kp[160K]
    float* Gf   = ws;
    float* Gr   = ws + 8388608;
    float* hs   = ws + 16777216;   // (NB*T, 512) = [h_fwd | h_rev | ctx]
    float* wat  = ws + 25165824;   // attention weights (NB,T,T); later reused
    float* qp   = ws + 33554432;
    float* kp   = ws + 33718272;
    float* Gd   = ws;              // reuse Gf+Gr region (16M floats)
    float* yenc = wat;             // reuse wat region: yenc = wat[0 : 4M)
    // decoder comm region (dead upper half of wat after kernel 7):
    //   hbuf: 2*NB*256 tagged 8B words (16384 ull = 32768 floats)
    //   lbuf: 2*NB*256 tagged 8B words
    ull* hbuf = (ull*)(wat + 4194304);
    ull* lbuf = hbuf + 16384;

    float* outp = (float*)d_out;
    const int M = NB * TSEQ;       // 16384
    dim3 blk(256);

    // 1-2. encoder input projections (biases folded in), time-major outputs
    gemm_nt<1><<<dim3(M / 64, 8), blk, 0, stream>>>(x, DB, Wih_f, DB, bih_f, bhh_f, Gf, 512, 512, DB);
    gemm_nt<2><<<dim3(M / 64, 8), blk, 0, stream>>>(x, DB, Wih_r, DB, bih_r, bhh_r, Gr, 512, 512, DB);
    // 3. bidirectional recurrence
    enc_scan<<<dim3(64), dim3(512), 0, stream>>>(Gf, Gr, Whh_f, Whh_r, hs);
    // 4-5. q/k projections (fc1 split)
    gemm_nt<0><<<dim3(M / 64, 1), blk, 0, stream>>>(hs, 512, fc1_w, 512, nullptr, nullptr, qp, 10, 10, 256);
    gemm_nt<0><<<dim3(M / 64, 1), blk, 0, stream>>>(hs, 512, fc1_w + 256, 512, nullptr, nullptr, kp, 10, 10, 256);
    // 6. attention scores + softmax
    attn_w<<<dim3(M), blk, 0, stream>>>(qp, kp, mask, fc2_w, wat);
    // 7. ctx = w @ hs  (writes hs cols 256:512)
    bgemm_nn<<<dim3(8, 4, NB), blk, 0, stream>>>(wat, hs);
    // 8. y_enc = [hs|ctx] @ fc3^T + b   (into wat[0:4M))
    gemm_nt<0><<<dim3(M / 64, 4), blk, 0, stream>>>(hs, 512, fc3_w, 512, fc3_b, nullptr, yenc, 256, 256, 512);
    // 8.5 decoder comm init (after wat's attention use is done)
    dec_init4<<<dim3(16), blk, 0, stream>>>(hs, hbuf, lbuf);
    // 9. decoder input projection, biases folded, time-major
    gemm_nt<1><<<dim3(M / 64, 16), blk, 0, stream>>>(yenc, 256, Wih_d, 272, bih_d, bhh_d, Gd, 1024, 1024, 256);
    // 10. decoder recurrence + classifier softmax (tag-sync, pinned reg weights)
    dec_scan4<<<dim3(128), blk, 0, stream>>>(Gd, Whh_d, Wih_d, lin_w, lin_b, hbuf, lbuf, outp);
}

// Round 7
// 3646.647 us; speedup vs baseline: 1.5585x; 1.5585x over previous
//
#include <hip/hip_runtime.h>

// Problem constants
#define TSEQ 512
#define NB   32     // batch
#define DB   768    // d_bert
#define H2E  128    // encoder hidden per dir
#define DL   256    // d_lstm
#define NC   16     // n_class

typedef unsigned long long ull;
typedef float f32x4 __attribute__((ext_vector_type(4)));

__device__ __forceinline__ float sigf(float x) { return 1.0f / (1.0f + __expf(-x)); }
__device__ __forceinline__ float tanhfast(float x) { return 1.0f - 2.0f / (1.0f + __expf(2.0f * x)); }

// ---------------------------------------------------------------------------
// Generic f32 GEMM: C[remap(m), n] = sum_k A[m,k]*W[n,k] + b1[n] + b2[n]
// 64x64 tile, BK=16, 256 threads, 4x4 microtile.
// MODE 0: direct rows. MODE 1: m=b*T+t -> out row t*NB+b. MODE 2: -> (T-1-t)*NB+b.
// ---------------------------------------------------------------------------
template <int MODE>
__global__ __launch_bounds__(256) void gemm_nt(
    const float* __restrict__ A, int lda,
    const float* __restrict__ W, int ldw,
    const float* __restrict__ b1, const float* __restrict__ b2,
    float* __restrict__ C, int ldc, int N, int K)
{
    __shared__ float As[16][68];
    __shared__ float Ws[16][68];
    const int tid = threadIdx.x;
    const int m0 = blockIdx.x * 64;
    const int n0 = blockIdx.y * 64;
    const int tx = tid & 15, ty = tid >> 4;
    const int lrow = tid >> 2;
    const int lk = (tid & 3) * 4;
    float acc[4][4] = {};

    for (int k0 = 0; k0 < K; k0 += 16) {
        float4 av = *(const float4*)(A + (size_t)(m0 + lrow) * lda + k0 + lk);
        float4 wv = make_float4(0.f, 0.f, 0.f, 0.f);
        if (n0 + lrow < N)
            wv = *(const float4*)(W + (size_t)(n0 + lrow) * ldw + k0 + lk);
        As[lk + 0][lrow] = av.x; As[lk + 1][lrow] = av.y;
        As[lk + 2][lrow] = av.z; As[lk + 3][lrow] = av.w;
        Ws[lk + 0][lrow] = wv.x; Ws[lk + 1][lrow] = wv.y;
        Ws[lk + 2][lrow] = wv.z; Ws[lk + 3][lrow] = wv.w;
        __syncthreads();
#pragma unroll
        for (int kk = 0; kk < 16; ++kk) {
            float a0 = As[kk][ty * 4 + 0], a1 = As[kk][ty * 4 + 1];
            float a2 = As[kk][ty * 4 + 2], a3 = As[kk][ty * 4 + 3];
            float w0 = Ws[kk][tx * 4 + 0], w1 = Ws[kk][tx * 4 + 1];
            float w2 = Ws[kk][tx * 4 + 2], w3 = Ws[kk][tx * 4 + 3];
            acc[0][0] += a0 * w0; acc[0][1] += a0 * w1; acc[0][2] += a0 * w2; acc[0][3] += a0 * w3;
            acc[1][0] += a1 * w0; acc[1][1] += a1 * w1; acc[1][2] += a1 * w2; acc[1][3] += a1 * w3;
            acc[2][0] += a2 * w0; acc[2][1] += a2 * w1; acc[2][2] += a2 * w2; acc[2][3] += a2 * w3;
            acc[3][0] += a3 * w0; acc[3][1] += a3 * w1; acc[3][2] += a3 * w2; acc[3][3] += a3 * w3;
        }
        __syncthreads();
    }

#pragma unroll
    for (int i = 0; i < 4; ++i) {
        int gm = m0 + ty * 4 + i;
        int orow;
        if (MODE == 0) orow = gm;
        else {
            int bb = gm >> 9;          // /TSEQ
            int tt = gm & (TSEQ - 1);
            orow = (MODE == 1 ? tt : (TSEQ - 1 - tt)) * NB + bb;
        }
#pragma unroll
        for (int j = 0; j < 4; ++j) {
            int gn = n0 + tx * 4 + j;
            if (gn < N) {
                float bias = (b1 ? b1[gn] : 0.f) + (b2 ? b2[gn] : 0.f);
                C[(size_t)orow * ldc + gn] = acc[i][j] + bias;
            }
        }
    }
}

// ---------------------------------------------------------------------------
// Encoder LSTM scan (unchanged).
// ---------------------------------------------------------------------------
__global__ __launch_bounds__(512) void enc_scan(
    const float* __restrict__ Gf, const float* __restrict__ Gr,
    const float* __restrict__ Whh_f, const float* __restrict__ Whh_r,
    float* __restrict__ hs_ctx)
{
    const int dir = blockIdx.x & 1;
    const int b = blockIdx.x >> 1;
    const float* __restrict__ G = dir ? Gr : Gf;
    const float* __restrict__ Whh = dir ? Whh_r : Whh_f;
    const int j = threadIdx.x;   // gate 0..511

    __shared__ float4 h4[H2E / 4];
    __shared__ float gates[4 * H2E];
    float* h_s = (float*)h4;

    float4 w[32];
#pragma unroll
    for (int k = 0; k < 32; ++k)
        w[k] = *(const float4*)(Whh + (size_t)j * H2E + k * 4);

    float c = 0.f;
    if (j < H2E) h_s[j] = 0.f;
    __syncthreads();

    for (int t = 0; t < TSEQ; ++t) {
        const float* grow = G + ((size_t)t * NB + b) * 512;
        float acc = grow[j];
#pragma unroll
        for (int k = 0; k < 32; ++k) {
            float4 hv = h4[k];
            acc += w[k].x * hv.x + w[k].y * hv.y + w[k].z * hv.z + w[k].w * hv.w;
        }
        gates[j] = acc;
        __syncthreads();
        if (j < H2E) {
            float ig = sigf(gates[j]);
            float fg = sigf(gates[j + H2E]);
            float gg = tanhfast(gates[j + 2 * H2E]);
            float og = sigf(gates[j + 3 * H2E]);
            c = fg * c + ig * gg;
            float h = og * tanhfast(c);
            h_s[j] = h;
            int tout = dir ? (TSEQ - 1 - t) : t;
            hs_ctx[((size_t)b * TSEQ + tout) * 512 + dir * H2E + j] = h;
        }
        __syncthreads();
    }
}

// ---------------------------------------------------------------------------
// Fused additive-attention scores + softmax (unchanged).
// ---------------------------------------------------------------------------
__global__ __launch_bounds__(256) void attn_w(
    const float* __restrict__ qp, const float* __restrict__ kp,
    const int* __restrict__ mask, const float* __restrict__ fc2,
    float* __restrict__ wout)
{
    const int bi = blockIdx.x;       // b*T + i
    const int b = bi >> 9;
    const int tid = threadIdx.x;
    __shared__ float kps[TSEQ * 11];
    __shared__ float red[8];

    const float* kpb = kp + (size_t)b * TSEQ * 10;
    for (int idx = tid; idx < TSEQ * 10; idx += 256) {
        int j = idx / 10, xx = idx - j * 10;
        kps[j * 11 + xx] = kpb[idx];
    }
    float q[10], vv[10];
#pragma unroll
    for (int xx = 0; xx < 10; ++xx) {
        q[xx] = qp[(size_t)bi * 10 + xx];
        vv[xx] = fc2[xx];
    }
    __syncthreads();

    float a[2];
#pragma unroll
    for (int jj = 0; jj < 2; ++jj) {
        int j = tid + jj * 256;
        float s = 0.f;
#pragma unroll
        for (int xx = 0; xx < 10; ++xx)
            s += vv[xx] * tanhfast(q[xx] + kps[j * 11 + xx]);
        if (mask[(size_t)b * TSEQ + j] == 0) s = -1e30f;
        a[jj] = s;
    }

    float m = fmaxf(a[0], a[1]);
#pragma unroll
    for (int o = 32; o >= 1; o >>= 1) m = fmaxf(m, __shfl_xor(m, o));
    if ((tid & 63) == 0) red[tid >> 6] = m;
    __syncthreads();
    m = fmaxf(fmaxf(red[0], red[1]), fmaxf(red[2], red[3]));

    float e0 = __expf(a[0] - m), e1 = __expf(a[1] - m);
    float s = e0 + e1;
#pragma unroll
    for (int o = 32; o >= 1; o >>= 1) s += __shfl_xor(s, o);
    if ((tid & 63) == 0) red[4 + (tid >> 6)] = s;
    __syncthreads();
    s = (red[4] + red[5]) + (red[6] + red[7]);
    float inv = 1.0f / s;
    wout[(size_t)bi * TSEQ + tid] = e0 * inv;
    wout[(size_t)bi * TSEQ + tid + 256] = e1 * inv;
}

// ---------------------------------------------------------------------------
// Batched NN GEMM: ctx = w @ hs (unchanged).
// ---------------------------------------------------------------------------
__global__ __launch_bounds__(256) void bgemm_nn(
    const float* __restrict__ Wmat,  // (NB, T, T)
    float* __restrict__ hs_ctx)      // (NB*T, 512): read cols [0,256), write [256,512)
{
    __shared__ float As[16][68];
    __shared__ float Bs[16][68];
    const int tid = threadIdx.x;
    const int b = blockIdx.z;
    const int i0 = blockIdx.x * 64;
    const int d0 = blockIdx.y * 64;
    const int tx = tid & 15, ty = tid >> 4;
    float acc[4][4] = {};
    const float* Ab = Wmat + (size_t)b * TSEQ * TSEQ;
    const float* Bb = hs_ctx + (size_t)b * TSEQ * 512;

    for (int k0 = 0; k0 < TSEQ; k0 += 16) {
        {
            int r = tid >> 2, kq = (tid & 3) * 4;
            float4 v = *(const float4*)(Ab + (size_t)(i0 + r) * TSEQ + k0 + kq);
            As[kq + 0][r] = v.x; As[kq + 1][r] = v.y; As[kq + 2][r] = v.z; As[kq + 3][r] = v.w;
        }
        {
            int kk = tid >> 4, dq = (tid & 15) * 4;
            float4 v = *(const float4*)(Bb + (size_t)(k0 + kk) * 512 + d0 + dq);
            *(float4*)&Bs[kk][dq] = v;
        }
        __syncthreads();
#pragma unroll
        for (int kk = 0; kk < 16; ++kk) {
            float a0 = As[kk][ty * 4 + 0], a1 = As[kk][ty * 4 + 1];
            float a2 = As[kk][ty * 4 + 2], a3 = As[kk][ty * 4 + 3];
            float b0 = Bs[kk][tx * 4 + 0], b1 = Bs[kk][tx * 4 + 1];
            float b2 = Bs[kk][tx * 4 + 2], b3 = Bs[kk][tx * 4 + 3];
            acc[0][0] += a0 * b0; acc[0][1] += a0 * b1; acc[0][2] += a0 * b2; acc[0][3] += a0 * b3;
            acc[1][0] += a1 * b0; acc[1][1] += a1 * b1; acc[1][2] += a1 * b2; acc[1][3] += a1 * b3;
            acc[2][0] += a2 * b0; acc[2][1] += a2 * b1; acc[2][2] += a2 * b2; acc[2][3] += a2 * b3;
            acc[3][0] += a3 * b0; acc[3][1] += a3 * b1; acc[3][2] += a3 * b2; acc[3][3] += a3 * b3;
        }
        __syncthreads();
    }
#pragma unroll
    for (int i = 0; i < 4; ++i)
#pragma unroll
        for (int j = 0; j < 4; ++j)
            hs_ctx[((size_t)b * TSEQ + i0 + ty * 4 + i) * 512 + 256 + d0 + tx * 4 + j] = acc[i][j];
}

// ---------------------------------------------------------------------------
// Decoder init: clear ALL tags in hbuf/lbuf (both parities), then write
// h(-1) (tag=1) into hbuf parity 0. Runs every launch (replay-safe).
// Words: (tag << 32) | f32 bits.
// ---------------------------------------------------------------------------
__global__ __launch_bounds__(256) void dec_init4(
    const float* __restrict__ hs_ctx, ull* hbuf, ull* lbuf)
{
    const int gid = blockIdx.x * 256 + threadIdx.x;
    for (int idx = gid; idx < 32768; idx += 16 * 256) {
        ull v = 0ull;
        if (idx < 8192) {            // hbuf parity 0: h(-1) with tag 1
            int b = idx >> 8, u = idx & 255;
            float hv = hs_ctx[((size_t)b * TSEQ + (TSEQ - 1)) * 512 + u];
            v = (1ull << 32) | (ull)__float_as_uint(hv);
        }
        ull* dst = (idx < 16384) ? (hbuf + idx) : (lbuf + (idx - 16384));
        __hip_atomic_store(dst, v, __ATOMIC_RELAXED, __HIP_MEMORY_SCOPE_AGENT);
    }
}

// ---------------------------------------------------------------------------
// Decoder scan v6: tag-carried sync with SMALL per-role spin loops.
// 128 blocks = 16 rg x 8 bg, 256 threads (4 waves).
//  - every thread verifies only its OWN 4 tagged h-words (sleep backoff)
//  - wave1 owns the y-path: polls the 16 tagged logit partials, softmax,
//    ylds + out — overlapped with other waves' h-verify
//  - y-term applied at finalize (wave0) from an LDS Wy slice, so the gate
//    dot starts as soon as h is ready (no softmax on the critical path)
//  - weights + Gd prefetched BEFORE the spin (sched_barrier pin), so L2
//    latency hides under the wait; launch_bounds(256,1) frees VGPR budget
// Publishing step s requires all blocks past step s-1 => parity ping-pong
// is WAR-safe; tags exact-match; dec_init4 resets tags each launch.
// ---------------------------------------------------------------------------
__global__ __launch_bounds__(256, 1) void dec_scan5(
    const float* __restrict__ Gd,     // (T, NB, 1024), biases folded
    const float* __restrict__ Whh,    // (1024, 256)
    const float* __restrict__ Wih,    // (1024, 272); cols 256:272 multiply y
    const float* __restrict__ lin_w,  // (16, 256)
    const float* __restrict__ lin_b,  // (16,)
    ull* hbuf,                        // (2, NB, 256) tagged h
    ull* lbuf,                        // (2, NB, 256) tagged logit partials
    float* __restrict__ out)          // (NB, T, NC)
{
    const int tid = threadIdx.x;
    const int rg  = blockIdx.x & 15;
    const int bg  = blockIdx.x >> 4;
    const int kseg = tid >> 6;        // wave id 0..3
    const int rr   = tid & 63;        // gate row 0..63 within block
    const int jrow = ((rr >> 4) << 8) + rg * 16 + (rr & 15);
    const bool isw1 = (kseg == 1);
    const int ybb = (tid >> 4) & 3;   // (bb,cls) for wave0 finalize / wave1 y
    const int ycls = tid & 15;

    __shared__ float hlds[4][260];    // h(t-1) per batch
    __shared__ float part[4][4][66];  // [bb][kseg][rr] gate partials
    __shared__ float ylds[4][17];     // y(t-1)
    __shared__ float hnew[4][17];     // new h slice (wave0-internal)
    __shared__ float linl[16][17];    // lin_w[cls][rg*16+u]
    __shared__ float wylds[64][17];   // y-weights for our 64 rows

    // one-time staging
    {
        int r = tid >> 2, c0 = (tid & 3) * 4;
        int j = ((r >> 4) << 8) + rg * 16 + (r & 15);
        const float* src = Wih + (size_t)j * 272 + 256 + c0;
        wylds[r][c0 + 0] = src[0]; wylds[r][c0 + 1] = src[1];
        wylds[r][c0 + 2] = src[2]; wylds[r][c0 + 3] = src[3];
    }
    linl[tid >> 4][tid & 15] = lin_w[(tid >> 4) * 256 + rg * 16 + (tid & 15)];
    const float lb = lin_b[ycls];
    const float* wbase = Whh + (size_t)jrow * 256 + kseg * 64;
    float cstate = 0.f;
    __syncthreads();

    for (int t = 0; t <= TSEQ; ++t) {
        const unsigned want = (unsigned)(t + 1);
        const ull* hsrc = hbuf + (size_t)(t & 1) * 8192 + (size_t)bg * 1024;
        const ull* lsrc = lbuf + (size_t)(t & 1) * 8192 + (size_t)bg * 1024;

        // ---- prefetch weights + Gd (independent of published data) ----
        f32x4 wv[16];
        float gv0 = 0.f, gv1 = 0.f, gv2 = 0.f, gv3 = 0.f;
        if (t < TSEQ) {
#pragma unroll
            for (int i = 0; i < 16; ++i) wv[i] = *(const f32x4*)(wbase + i * 4);
            if (kseg == 0) {
                const float* gb = Gd + ((size_t)t * NB + bg * 4) * 1024 + jrow;
                gv0 = gb[0]; gv1 = gb[1024]; gv2 = gb[2048]; gv3 = gb[3072];
            }
        }
        __builtin_amdgcn_sched_barrier(0);

        // ---- wave1: y-path (poll tagged logit partials, softmax, out) ----
        if (isw1) {
            float yv = 0.f;
            if (t > 0) {
                float lsum;
                for (;;) {
                    lsum = lb;
                    bool ok = true;
#pragma unroll
                    for (int r = 0; r < 16; ++r) {
                        ull lv = __hip_atomic_load(lsrc + ybb * 256 + r * 16 + ycls,
                                                   __ATOMIC_RELAXED, __HIP_MEMORY_SCOPE_AGENT);
                        ok &= ((unsigned)(lv >> 32) == want);
                        lsum += __uint_as_float((unsigned)lv);
                    }
                    if (ok) break;
                    __builtin_amdgcn_s_sleep(2);
                }
                float m = lsum;
#pragma unroll
                for (int o = 1; o < 16; o <<= 1) m = fmaxf(m, __shfl_xor(m, o, 16));
                float e = __expf(lsum - m);
                float ss = e;
#pragma unroll
                for (int o = 1; o < 16; o <<= 1) ss += __shfl_xor(ss, o, 16);
                yv = e / ss;
                if (rg == 0)
                    out[(((size_t)(bg * 4 + ybb)) * TSEQ + (t - 1)) * NC + ycls] = yv;
            }
            ylds[ybb][ycls] = yv;
        }

        // ---- all threads: verify + load own 4 tagged h-words ----
        {
            ull h0, h1, h2, h3;
            for (;;) {
                h0 = __hip_atomic_load(hsrc + tid,       __ATOMIC_RELAXED, __HIP_MEMORY_SCOPE_AGENT);
                h1 = __hip_atomic_load(hsrc + tid + 256, __ATOMIC_RELAXED, __HIP_MEMORY_SCOPE_AGENT);
                h2 = __hip_atomic_load(hsrc + tid + 512, __ATOMIC_RELAXED, __HIP_MEMORY_SCOPE_AGENT);
                h3 = __hip_atomic_load(hsrc + tid + 768, __ATOMIC_RELAXED, __HIP_MEMORY_SCOPE_AGENT);
                if (((unsigned)(h0 >> 32) == want) && ((unsigned)(h1 >> 32) == want) &&
                    ((unsigned)(h2 >> 32) == want) && ((unsigned)(h3 >> 32) == want))
                    break;
                __builtin_amdgcn_s_sleep(2);
            }
            hlds[0][tid] = __uint_as_float((unsigned)h0);
            hlds[1][tid] = __uint_as_float((unsigned)h1);
            hlds[2][tid] = __uint_as_float((unsigned)h2);
            hlds[3][tid] = __uint_as_float((unsigned)h3);
        }
        __syncthreads();   // hlds + ylds ready

        if (t == TSEQ) break;   // uniform

        // ---- gate partials: prefetched weights x broadcast h ----
        {
            float a0 = gv0, a1 = gv1, a2 = gv2, a3 = gv3;
#pragma unroll
            for (int i = 0; i < 16; ++i) {
                const f32x4 w = wv[i];
                const int kc = kseg * 64 + i * 4;
                f32x4 p0 = *(const f32x4*)&hlds[0][kc];
                f32x4 p1 = *(const f32x4*)&hlds[1][kc];
                f32x4 p2 = *(const f32x4*)&hlds[2][kc];
                f32x4 p3 = *(const f32x4*)&hlds[3][kc];
                a0 += w.x * p0.x + w.y * p0.y + w.z * p0.z + w.w * p0.w;
                a1 += w.x * p1.x + w.y * p1.y + w.z * p1.z + w.w * p1.w;
                a2 += w.x * p2.x + w.y * p2.y + w.z * p2.z + w.w * p2.w;
                a3 += w.x * p3.x + w.y * p3.y + w.z * p3.z + w.w * p3.w;
            }
            part[0][kseg][rr] = a0;
            part[1][kseg][rr] = a1;
            part[2][kseg][rr] = a2;
            part[3][kseg][rr] = a3;
        }
        __syncthreads();   // part ready

        // ---- finalize (wave0): ksegs + y-term, nonlinearity, publish ----
        if (tid < 64) {
            const int bb = ybb, u = ycls;
            float g[4];
#pragma unroll
            for (int q = 0; q < 4; ++q) {
                const int r = q * 16 + u;
                float s = part[bb][0][r] + part[bb][1][r]
                        + part[bb][2][r] + part[bb][3][r];
#pragma unroll
                for (int c = 0; c < 16; ++c)
                    s += wylds[r][c] * ylds[bb][c];
                g[q] = s;
            }
            float ig = sigf(g[0]), fg = sigf(g[1]);
            float gv = tanhfast(g[2]), og = sigf(g[3]);
            cstate = fg * cstate + ig * gv;
            float h = og * tanhfast(cstate);
            hnew[bb][u] = h;
            const ull tagbits = ((ull)(unsigned)(t + 2)) << 32;
            const size_t oidx = (size_t)((t + 1) & 1) * 8192
                              + (size_t)(bg * 4 + bb) * 256 + rg * 16 + u;
            __hip_atomic_store(hbuf + oidx, tagbits | (ull)__float_as_uint(h),
                               __ATOMIC_RELAXED, __HIP_MEMORY_SCOPE_AGENT);
            // partial logit (bb, cls=u) over this block's 16 h-units
            float lp = 0.f;
#pragma unroll
            for (int u2 = 0; u2 < 16; ++u2)
                lp += linl[u][u2] * hnew[bb][u2];
            __hip_atomic_store(lbuf + oidx, tagbits | (ull)__float_as_uint(lp),
                               __ATOMIC_RELAXED, __HIP_MEMORY_SCOPE_AGENT);
        }
        // no trailing barrier: next-step verify self-gates on our publish
    }
}

// ---------------------------------------------------------------------------
extern "C" void kernel_launch(void* const* d_in, const int* in_sizes, int n_in,
                              void* d_out, int out_size, void* d_ws, size_t ws_size,
                              hipStream_t stream)
{
    const float* x     = (const float*)d_in[0];
    const int*   mask  = (const int*)d_in[1];
    const float* Wih_f = (const float*)d_in[2];
    const float* Whh_f = (const float*)d_in[3];
    const float* bih_f = (const float*)d_in[4];
    const float* bhh_f = (const float*)d_in[5];
    const float* Wih_r = (const float*)d_in[6];
    const float* Whh_r = (const float*)d_in[7];
    const float* bih_r = (const float*)d_in[8];
    const float* bhh_r = (const float*)d_in[9];
    const float* fc1_w = (const float*)d_in[10];
    const float* fc2_w = (const float*)d_in[11];
    const float* fc3_w = (const float*)d_in[12];
    const float* fc3_b = (const float*)d_in[13];
    const float* Wih_d = (const float*)d_in[14];
    const float* Whh_d = (const float*)d_in[15];
    const float* bih_d = (const float*)d_in[16];
    const float* bhh_d = (const float*)d_in[17];
    const float* lin_w = (const float*)d_in[18];
    const float* lin_b = (const float*)d_in[19];

    float* ws = (float*)d_ws;
    // layout (floats): Gf[8M] Gr[8M] hs[8M] wat[8M] qp[160K] kp[160K]
    float* Gf   = ws;
    float* Gr   = ws + 8388608;
    float* hs   = ws + 16777216;   // (NB*T, 512) = [h_fwd | h_rev | ctx]
    float* wat  = ws + 25165824;   // attention weights (NB,T,T); later reused
    float* qp   = ws + 33554432;
    float* kp   = ws + 33718272;
    float* Gd   = ws;              // reuse Gf+Gr region (16M floats)
    float* yenc = wat;             // reuse wat region: yenc = wat[0 : 4M)
    // decoder comm region (dead upper half of wat after kernel 7):
    ull* hbuf = (ull*)(wat + 4194304);   // 2*NB*256 tagged 8B words
    ull* lbuf = hbuf + 16384;

    float* outp = (float*)d_out;
    const int M = NB * TSEQ;       // 16384
    dim3 blk(256);

    // 1-2. encoder input projections (biases folded in), time-major outputs
    gemm_nt<1><<<dim3(M / 64, 8), blk, 0, stream>>>(x, DB, Wih_f, DB, bih_f, bhh_f, Gf, 512, 512, DB);
    gemm_nt<2><<<dim3(M / 64, 8), blk, 0, stream>>>(x, DB, Wih_r, DB, bih_r, bhh_r, Gr, 512, 512, DB);
    // 3. bidirectional recurrence
    enc_scan<<<dim3(64), dim3(512), 0, stream>>>(Gf, Gr, Whh_f, Whh_r, hs);
    // 4-5. q/k projections (fc1 split)
    gemm_nt<0><<<dim3(M / 64, 1), blk, 0, stream>>>(hs, 512, fc1_w, 512, nullptr, nullptr, qp, 10, 10, 256);
    gemm_nt<0><<<dim3(M / 64, 1), blk, 0, stream>>>(hs, 512, fc1_w + 256, 512, nullptr, nullptr, kp, 10, 10, 256);
    // 6. attention scores + softmax
    attn_w<<<dim3(M), blk, 0, stream>>>(qp, kp, mask, fc2_w, wat);
    // 7. ctx = w @ hs  (writes hs cols 256:512)
    bgemm_nn<<<dim3(8, 4, NB), blk, 0, stream>>>(wat, hs);
    // 8. y_enc = [hs|ctx] @ fc3^T + b   (into wat[0:4M))
    gemm_nt<0><<<dim3(M / 64, 4), blk, 0, stream>>>(hs, 512, fc3_w, 512, fc3_b, nullptr, yenc, 256, 256, 512);
    // 8.5 decoder comm init (after wat's attention use is done)
    dec_init4<<<dim3(16), blk, 0, stream>>>(hs, hbuf, lbuf);
    // 9. decoder input projection, biases folded, time-major
    gemm_nt<1><<<dim3(M / 64, 16), blk, 0, stream>>>(yenc, 256, Wih_d, 272, bih_d, bhh_d, Gd, 1024, 1024, 256);
    // 10. decoder recurrence + classifier softmax (small-spin tag sync)
    dec_scan5<<<dim3(128), blk, 0, stream>>>(Gd, Whh_d, Wih_d, lin_w, lin_b, hbuf, lbuf, outp);
}

// Round 8
// 3398.906 us; speedup vs baseline: 1.6720x; 1.0729x over previous
//
#include <hip/hip_runtime.h>

// Problem constants
#define TSEQ 512
#define NB   32     // batch
#define DB   768    // d_bert
#define H2E  128    // encoder hidden per dir
#define DL   256    // d_lstm
#define NC   16     // n_class

typedef unsigned long long ull;
typedef float f32x4 __attribute__((ext_vector_type(4)));

__device__ __forceinline__ float sigf(float x) { return 1.0f / (1.0f + __expf(-x)); }
__device__ __forceinline__ float tanhfast(float x) { return 1.0f - 2.0f / (1.0f + __expf(2.0f * x)); }

// ---------------------------------------------------------------------------
// f32 GEMM, 64x64 tile (kept for tiny-N q/k projections).
// ---------------------------------------------------------------------------
template <int MODE>
__global__ __launch_bounds__(256) void gemm_nt(
    const float* __restrict__ A, int lda,
    const float* __restrict__ W, int ldw,
    const float* __restrict__ b1, const float* __restrict__ b2,
    float* __restrict__ C, int ldc, int N, int K)
{
    __shared__ float As[16][68];
    __shared__ float Ws[16][68];
    const int tid = threadIdx.x;
    const int m0 = blockIdx.x * 64;
    const int n0 = blockIdx.y * 64;
    const int tx = tid & 15, ty = tid >> 4;
    const int lrow = tid >> 2;
    const int lk = (tid & 3) * 4;
    float acc[4][4] = {};

    for (int k0 = 0; k0 < K; k0 += 16) {
        float4 av = *(const float4*)(A + (size_t)(m0 + lrow) * lda + k0 + lk);
        float4 wv = make_float4(0.f, 0.f, 0.f, 0.f);
        if (n0 + lrow < N)
            wv = *(const float4*)(W + (size_t)(n0 + lrow) * ldw + k0 + lk);
        As[lk + 0][lrow] = av.x; As[lk + 1][lrow] = av.y;
        As[lk + 2][lrow] = av.z; As[lk + 3][lrow] = av.w;
        Ws[lk + 0][lrow] = wv.x; Ws[lk + 1][lrow] = wv.y;
        Ws[lk + 2][lrow] = wv.z; Ws[lk + 3][lrow] = wv.w;
        __syncthreads();
#pragma unroll
        for (int kk = 0; kk < 16; ++kk) {
            float a0 = As[kk][ty * 4 + 0], a1 = As[kk][ty * 4 + 1];
            float a2 = As[kk][ty * 4 + 2], a3 = As[kk][ty * 4 + 3];
            float w0 = Ws[kk][tx * 4 + 0], w1 = Ws[kk][tx * 4 + 1];
            float w2 = Ws[kk][tx * 4 + 2], w3 = Ws[kk][tx * 4 + 3];
            acc[0][0] += a0 * w0; acc[0][1] += a0 * w1; acc[0][2] += a0 * w2; acc[0][3] += a0 * w3;
            acc[1][0] += a1 * w0; acc[1][1] += a1 * w1; acc[1][2] += a1 * w2; acc[1][3] += a1 * w3;
            acc[2][0] += a2 * w0; acc[2][1] += a2 * w1; acc[2][2] += a2 * w2; acc[2][3] += a2 * w3;
            acc[3][0] += a3 * w0; acc[3][1] += a3 * w1; acc[3][2] += a3 * w2; acc[3][3] += a3 * w3;
        }
        __syncthreads();
    }

#pragma unroll
    for (int i = 0; i < 4; ++i) {
        int gm = m0 + ty * 4 + i;
        int orow;
        if (MODE == 0) orow = gm;
        else {
            int bb = gm >> 9;
            int tt = gm & (TSEQ - 1);
            orow = (MODE == 1 ? tt : (TSEQ - 1 - tt)) * NB + bb;
        }
#pragma unroll
        for (int j = 0; j < 4; ++j) {
            int gn = n0 + tx * 4 + j;
            if (gn < N) {
                float bias = (b1 ? b1[gn] : 0.f) + (b2 ? b2[gn] : 0.f);
                C[(size_t)orow * ldc + gn] = acc[i][j] + bias;
            }
        }
    }
}

// ---------------------------------------------------------------------------
// f32 GEMM, 128x64 tile, 8x4 microtile (32 FMA : 12 LDS reads per kk).
// Same remap modes. M multiple of 128, K multiple of 16, N guarded.
// ---------------------------------------------------------------------------
template <int MODE>
__global__ __launch_bounds__(256) void gemm_nt128(
    const float* __restrict__ A, int lda,
    const float* __restrict__ W, int ldw,
    const float* __restrict__ b1, const float* __restrict__ b2,
    float* __restrict__ C, int ldc, int N, int K)
{
    __shared__ float As[16][132];
    __shared__ float Ws[16][68];
    const int tid = threadIdx.x;
    const int m0 = blockIdx.x * 128;
    const int n0 = blockIdx.y * 64;
    const int tx = tid & 15, ty = tid >> 4;
    const int lrow = tid >> 1, lk = (tid & 1) * 8;   // A staging
    const int wrow = tid >> 2, wk = (tid & 3) * 4;   // W staging
    float acc[8][4] = {};

    for (int k0 = 0; k0 < K; k0 += 16) {
        float4 a0v = *(const float4*)(A + (size_t)(m0 + lrow) * lda + k0 + lk);
        float4 a1v = *(const float4*)(A + (size_t)(m0 + lrow) * lda + k0 + lk + 4);
        float4 wv = make_float4(0.f, 0.f, 0.f, 0.f);
        if (n0 + wrow < N)
            wv = *(const float4*)(W + (size_t)(n0 + wrow) * ldw + k0 + wk);
        As[lk + 0][lrow] = a0v.x; As[lk + 1][lrow] = a0v.y;
        As[lk + 2][lrow] = a0v.z; As[lk + 3][lrow] = a0v.w;
        As[lk + 4][lrow] = a1v.x; As[lk + 5][lrow] = a1v.y;
        As[lk + 6][lrow] = a1v.z; As[lk + 7][lrow] = a1v.w;
        Ws[wk + 0][wrow] = wv.x; Ws[wk + 1][wrow] = wv.y;
        Ws[wk + 2][wrow] = wv.z; Ws[wk + 3][wrow] = wv.w;
        __syncthreads();
#pragma unroll
        for (int kk = 0; kk < 16; ++kk) {
            float a[8], w[4];
#pragma unroll
            for (int i = 0; i < 8; ++i) a[i] = As[kk][ty * 8 + i];
#pragma unroll
            for (int j = 0; j < 4; ++j) w[j] = Ws[kk][tx * 4 + j];
#pragma unroll
            for (int i = 0; i < 8; ++i)
#pragma unroll
                for (int j = 0; j < 4; ++j)
                    acc[i][j] += a[i] * w[j];
        }
        __syncthreads();
    }

#pragma unroll
    for (int i = 0; i < 8; ++i) {
        int gm = m0 + ty * 8 + i;
        int orow;
        if (MODE == 0) orow = gm;
        else {
            int bb = gm >> 9;
            int tt = gm & (TSEQ - 1);
            orow = (MODE == 1 ? tt : (TSEQ - 1 - tt)) * NB + bb;
        }
#pragma unroll
        for (int j = 0; j < 4; ++j) {
            int gn = n0 + tx * 4 + j;
            if (gn < N) {
                float bias = (b1 ? b1[gn] : 0.f) + (b2 ? b2[gn] : 0.f);
                C[(size_t)orow * ldc + gn] = acc[i][j] + bias;
            }
        }
    }
}

// ---------------------------------------------------------------------------
// Encoder LSTM scan (unchanged).
// ---------------------------------------------------------------------------
__global__ __launch_bounds__(512) void enc_scan(
    const float* __restrict__ Gf, const float* __restrict__ Gr,
    const float* __restrict__ Whh_f, const float* __restrict__ Whh_r,
    float* __restrict__ hs_ctx)
{
    const int dir = blockIdx.x & 1;
    const int b = blockIdx.x >> 1;
    const float* __restrict__ G = dir ? Gr : Gf;
    const float* __restrict__ Whh = dir ? Whh_r : Whh_f;
    const int j = threadIdx.x;

    __shared__ float4 h4[H2E / 4];
    __shared__ float gates[4 * H2E];
    float* h_s = (float*)h4;

    float4 w[32];
#pragma unroll
    for (int k = 0; k < 32; ++k)
        w[k] = *(const float4*)(Whh + (size_t)j * H2E + k * 4);

    float c = 0.f;
    if (j < H2E) h_s[j] = 0.f;
    __syncthreads();

    for (int t = 0; t < TSEQ; ++t) {
        const float* grow = G + ((size_t)t * NB + b) * 512;
        float acc = grow[j];
#pragma unroll
        for (int k = 0; k < 32; ++k) {
            float4 hv = h4[k];
            acc += w[k].x * hv.x + w[k].y * hv.y + w[k].z * hv.z + w[k].w * hv.w;
        }
        gates[j] = acc;
        __syncthreads();
        if (j < H2E) {
            float ig = sigf(gates[j]);
            float fg = sigf(gates[j + H2E]);
            float gg = tanhfast(gates[j + 2 * H2E]);
            float og = sigf(gates[j + 3 * H2E]);
            c = fg * c + ig * gg;
            float h = og * tanhfast(c);
            h_s[j] = h;
            int tout = dir ? (TSEQ - 1 - t) : t;
            hs_ctx[((size_t)b * TSEQ + tout) * 512 + dir * H2E + j] = h;
        }
        __syncthreads();
    }
}

// ---------------------------------------------------------------------------
// Fused additive-attention scores + softmax (unchanged).
// ---------------------------------------------------------------------------
__global__ __launch_bounds__(256) void attn_w(
    const float* __restrict__ qp, const float* __restrict__ kp,
    const int* __restrict__ mask, const float* __restrict__ fc2,
    float* __restrict__ wout)
{
    const int bi = blockIdx.x;
    const int b = bi >> 9;
    const int tid = threadIdx.x;
    __shared__ float kps[TSEQ * 11];
    __shared__ float red[8];

    const float* kpb = kp + (size_t)b * TSEQ * 10;
    for (int idx = tid; idx < TSEQ * 10; idx += 256) {
        int j = idx / 10, xx = idx - j * 10;
        kps[j * 11 + xx] = kpb[idx];
    }
    float q[10], vv[10];
#pragma unroll
    for (int xx = 0; xx < 10; ++xx) {
        q[xx] = qp[(size_t)bi * 10 + xx];
        vv[xx] = fc2[xx];
    }
    __syncthreads();

    float a[2];
#pragma unroll
    for (int jj = 0; jj < 2; ++jj) {
        int j = tid + jj * 256;
        float s = 0.f;
#pragma unroll
        for (int xx = 0; xx < 10; ++xx)
            s += vv[xx] * tanhfast(q[xx] + kps[j * 11 + xx]);
        if (mask[(size_t)b * TSEQ + j] == 0) s = -1e30f;
        a[jj] = s;
    }

    float m = fmaxf(a[0], a[1]);
#pragma unroll
    for (int o = 32; o >= 1; o >>= 1) m = fmaxf(m, __shfl_xor(m, o));
    if ((tid & 63) == 0) red[tid >> 6] = m;
    __syncthreads();
    m = fmaxf(fmaxf(red[0], red[1]), fmaxf(red[2], red[3]));

    float e0 = __expf(a[0] - m), e1 = __expf(a[1] - m);
    float s = e0 + e1;
#pragma unroll
    for (int o = 32; o >= 1; o >>= 1) s += __shfl_xor(s, o);
    if ((tid & 63) == 0) red[4 + (tid >> 6)] = s;
    __syncthreads();
    s = (red[4] + red[5]) + (red[6] + red[7]);
    float inv = 1.0f / s;
    wout[(size_t)bi * TSEQ + tid] = e0 * inv;
    wout[(size_t)bi * TSEQ + tid + 256] = e1 * inv;
}

// ---------------------------------------------------------------------------
// Batched NN GEMM: ctx = w @ hs (unchanged).
// ---------------------------------------------------------------------------
__global__ __launch_bounds__(256) void bgemm_nn(
    const float* __restrict__ Wmat,
    float* __restrict__ hs_ctx)
{
    __shared__ float As[16][68];
    __shared__ float Bs[16][68];
    const int tid = threadIdx.x;
    const int b = blockIdx.z;
    const int i0 = blockIdx.x * 64;
    const int d0 = blockIdx.y * 64;
    const int tx = tid & 15, ty = tid >> 4;
    float acc[4][4] = {};
    const float* Ab = Wmat + (size_t)b * TSEQ * TSEQ;
    const float* Bb = hs_ctx + (size_t)b * TSEQ * 512;

    for (int k0 = 0; k0 < TSEQ; k0 += 16) {
        {
            int r = tid >> 2, kq = (tid & 3) * 4;
            float4 v = *(const float4*)(Ab + (size_t)(i0 + r) * TSEQ + k0 + kq);
            As[kq + 0][r] = v.x; As[kq + 1][r] = v.y; As[kq + 2][r] = v.z; As[kq + 3][r] = v.w;
        }
        {
            int kk = tid >> 4, dq = (tid & 15) * 4;
            float4 v = *(const float4*)(Bb + (size_t)(k0 + kk) * 512 + d0 + dq);
            *(float4*)&Bs[kk][dq] = v;
        }
        __syncthreads();
#pragma unroll
        for (int kk = 0; kk < 16; ++kk) {
            float a0 = As[kk][ty * 4 + 0], a1 = As[kk][ty * 4 + 1];
            float a2 = As[kk][ty * 4 + 2], a3 = As[kk][ty * 4 + 3];
            float b0 = Bs[kk][tx * 4 + 0], b1 = Bs[kk][tx * 4 + 1];
            float b2 = Bs[kk][tx * 4 + 2], b3 = Bs[kk][tx * 4 + 3];
            acc[0][0] += a0 * b0; acc[0][1] += a0 * b1; acc[0][2] += a0 * b2; acc[0][3] += a0 * b3;
            acc[1][0] += a1 * b0; acc[1][1] += a1 * b1; acc[1][2] += a1 * b2; acc[1][3] += a1 * b3;
            acc[2][0] += a2 * b0; acc[2][1] += a2 * b1; acc[2][2] += a2 * b2; acc[2][3] += a2 * b3;
            acc[3][0] += a3 * b0; acc[3][1] += a3 * b1; acc[3][2] += a3 * b2; acc[3][3] += a3 * b3;
        }
        __syncthreads();
    }
#pragma unroll
    for (int i = 0; i < 4; ++i)
#pragma unroll
        for (int j = 0; j < 4; ++j)
            hs_ctx[((size_t)b * TSEQ + i0 + ty * 4 + i) * 512 + 256 + d0 + tx * 4 + j] = acc[i][j];
}

// ---------------------------------------------------------------------------
// Decoder init (unchanged): clear all tags, seed h(-1) tag=1 parity 0.
// ---------------------------------------------------------------------------
__global__ __launch_bounds__(256) void dec_init4(
    const float* __restrict__ hs_ctx, ull* hbuf, ull* lbuf)
{
    const int gid = blockIdx.x * 256 + threadIdx.x;
    for (int idx = gid; idx < 32768; idx += 16 * 256) {
        ull v = 0ull;
        if (idx < 8192) {
            int b = idx >> 8, u = idx & 255;
            float hv = hs_ctx[((size_t)b * TSEQ + (TSEQ - 1)) * 512 + u];
            v = (1ull << 32) | (ull)__float_as_uint(hv);
        }
        ull* dst = (idx < 16384) ? (hbuf + idx) : (lbuf + (idx - 16384));
        __hip_atomic_store(dst, v, __ATOMIC_RELAXED, __HIP_MEMORY_SCOPE_AGENT);
    }
}

// ---------------------------------------------------------------------------
// Decoder scan v7: dec_scan5's tag sync + Whh slice in LDS (odd stride 257
// -> per-row b32 reads are 2-way/conflict-free; 64 KB read/block/step from
// LDS instead of L2, no register-allocator fights). Weights staged ONCE.
// ---------------------------------------------------------------------------
__global__ __launch_bounds__(256) void dec_scan6(
    const float* __restrict__ Gd,     // (T, NB, 1024), biases folded
    const float* __restrict__ Whh,    // (1024, 256)
    const float* __restrict__ Wih,    // (1024, 272); cols 256:272 multiply y
    const float* __restrict__ lin_w,  // (16, 256)
    const float* __restrict__ lin_b,  // (16,)
    ull* hbuf,                        // (2, NB, 256) tagged h
    ull* lbuf,                        // (2, NB, 256) tagged logit partials
    float* __restrict__ out)          // (NB, T, NC)
{
    const int tid = threadIdx.x;
    const int rg  = blockIdx.x & 15;
    const int bg  = blockIdx.x >> 4;
    const int kseg = tid >> 6;        // wave id 0..3
    const int rr   = tid & 63;        // gate row 0..63 within block
    const bool isw1 = (kseg == 1);
    const int ybb = (tid >> 4) & 3;
    const int ycls = tid & 15;

    __shared__ float wlds[64][257];   // Whh slice, odd stride (bank-clean b32)
    __shared__ float hlds[4][260];    // h(t-1) per batch
    __shared__ float part[4][4][66];  // [bb][kseg][rr] gate partials
    __shared__ float ylds[4][17];     // y(t-1)
    __shared__ float hnew[4][17];     // new h slice (wave0-internal)
    __shared__ float linl[16][17];    // lin_w[cls][rg*16+u]
    __shared__ float wylds[64][17];   // y-weights for our 64 rows

    // ---- one-time staging ----
    for (int idx = tid; idx < 64 * 256; idx += 256) {
        int row = idx >> 8, c = idx & 255;
        int j = ((row >> 4) << 8) + rg * 16 + (row & 15);
        wlds[row][c] = Whh[(size_t)j * 256 + c];
    }
    {
        int r = tid >> 2, c0 = (tid & 3) * 4;
        int j = ((r >> 4) << 8) + rg * 16 + (r & 15);
        const float* src = Wih + (size_t)j * 272 + 256 + c0;
        wylds[r][c0 + 0] = src[0]; wylds[r][c0 + 1] = src[1];
        wylds[r][c0 + 2] = src[2]; wylds[r][c0 + 3] = src[3];
    }
    linl[tid >> 4][tid & 15] = lin_w[(tid >> 4) * 256 + rg * 16 + (tid & 15)];
    const float lb = lin_b[ycls];
    const int jrow = ((rr >> 4) << 8) + rg * 16 + (rr & 15);
    float cstate = 0.f;
    __syncthreads();

    for (int t = 0; t <= TSEQ; ++t) {
        const unsigned want = (unsigned)(t + 1);
        const ull* hsrc = hbuf + (size_t)(t & 1) * 8192 + (size_t)bg * 1024;
        const ull* lsrc = lbuf + (size_t)(t & 1) * 8192 + (size_t)bg * 1024;

        // Gd prefetch (h-independent), wave0 only
        float gv0 = 0.f, gv1 = 0.f, gv2 = 0.f, gv3 = 0.f;
        if (kseg == 0 && t < TSEQ) {
            const float* gb = Gd + ((size_t)t * NB + bg * 4) * 1024 + jrow;
            gv0 = gb[0]; gv1 = gb[1024]; gv2 = gb[2048]; gv3 = gb[3072];
        }
        __builtin_amdgcn_sched_barrier(0);

        // ---- wave1: y-path (poll tagged logit partials, softmax, out) ----
        if (isw1) {
            float yv = 0.f;
            if (t > 0) {
                float lsum;
                for (;;) {
                    lsum = lb;
                    bool ok = true;
#pragma unroll
                    for (int r = 0; r < 16; ++r) {
                        ull lv = __hip_atomic_load(lsrc + ybb * 256 + r * 16 + ycls,
                                                   __ATOMIC_RELAXED, __HIP_MEMORY_SCOPE_AGENT);
                        ok &= ((unsigned)(lv >> 32) == want);
                        lsum += __uint_as_float((unsigned)lv);
                    }
                    if (ok) break;
                    __builtin_amdgcn_s_sleep(1);
                }
                float m = lsum;
#pragma unroll
                for (int o = 1; o < 16; o <<= 1) m = fmaxf(m, __shfl_xor(m, o, 16));
                float e = __expf(lsum - m);
                float ss = e;
#pragma unroll
                for (int o = 1; o < 16; o <<= 1) ss += __shfl_xor(ss, o, 16);
                yv = e / ss;
                if (rg == 0)
                    out[(((size_t)(bg * 4 + ybb)) * TSEQ + (t - 1)) * NC + ycls] = yv;
            }
            ylds[ybb][ycls] = yv;
        }

        // ---- all threads: verify + load own 4 tagged h-words ----
        {
            ull h0, h1, h2, h3;
            for (;;) {
                h0 = __hip_atomic_load(hsrc + tid,       __ATOMIC_RELAXED, __HIP_MEMORY_SCOPE_AGENT);
                h1 = __hip_atomic_load(hsrc + tid + 256, __ATOMIC_RELAXED, __HIP_MEMORY_SCOPE_AGENT);
                h2 = __hip_atomic_load(hsrc + tid + 512, __ATOMIC_RELAXED, __HIP_MEMORY_SCOPE_AGENT);
                h3 = __hip_atomic_load(hsrc + tid + 768, __ATOMIC_RELAXED, __HIP_MEMORY_SCOPE_AGENT);
                if (((unsigned)(h0 >> 32) == want) && ((unsigned)(h1 >> 32) == want) &&
                    ((unsigned)(h2 >> 32) == want) && ((unsigned)(h3 >> 32) == want))
                    break;
                __builtin_amdgcn_s_sleep(1);
            }
            hlds[0][tid] = __uint_as_float((unsigned)h0);
            hlds[1][tid] = __uint_as_float((unsigned)h1);
            hlds[2][tid] = __uint_as_float((unsigned)h2);
            hlds[3][tid] = __uint_as_float((unsigned)h3);
        }
        __syncthreads();   // hlds + ylds ready

        if (t == TSEQ) break;

        // ---- gate partials: weights from LDS (own row), h broadcast ----
        {
            float a0 = gv0, a1 = gv1, a2 = gv2, a3 = gv3;
            const float* wrow = &wlds[rr][kseg * 64];
#pragma unroll
            for (int i = 0; i < 16; ++i) {
                const int kc = kseg * 64 + i * 4;
                f32x4 p0 = *(const f32x4*)&hlds[0][kc];
                f32x4 p1 = *(const f32x4*)&hlds[1][kc];
                f32x4 p2 = *(const f32x4*)&hlds[2][kc];
                f32x4 p3 = *(const f32x4*)&hlds[3][kc];
                float w0 = wrow[i * 4 + 0], w1 = wrow[i * 4 + 1];
                float w2 = wrow[i * 4 + 2], w3 = wrow[i * 4 + 3];
                a0 += w0 * p0.x + w1 * p0.y + w2 * p0.z + w3 * p0.w;
                a1 += w0 * p1.x + w1 * p1.y + w2 * p1.z + w3 * p1.w;
                a2 += w0 * p2.x + w1 * p2.y + w2 * p2.z + w3 * p2.w;
                a3 += w0 * p3.x + w1 * p3.y + w2 * p3.z + w3 * p3.w;
            }
            part[0][kseg][rr] = a0;
            part[1][kseg][rr] = a1;
            part[2][kseg][rr] = a2;
            part[3][kseg][rr] = a3;
        }
        __syncthreads();   // part ready

        // ---- finalize (wave0): ksegs + y-term, nonlinearity, publish ----
        if (tid < 64) {
            const int bb = ybb, u = ycls;
            float g[4];
#pragma unroll
            for (int q = 0; q < 4; ++q) {
                const int r = q * 16 + u;
                float s = part[bb][0][r] + part[bb][1][r]
                        + part[bb][2][r] + part[bb][3][r];
#pragma unroll
                for (int c = 0; c < 16; ++c)
                    s += wylds[r][c] * ylds[bb][c];
                g[q] = s;
            }
            float ig = sigf(g[0]), fg = sigf(g[1]);
            float gv = tanhfast(g[2]), og = sigf(g[3]);
            cstate = fg * cstate + ig * gv;
            float h = og * tanhfast(cstate);
            hnew[bb][u] = h;
            const ull tagbits = ((ull)(unsigned)(t + 2)) << 32;
            const size_t oidx = (size_t)((t + 1) & 1) * 8192
                              + (size_t)(bg * 4 + bb) * 256 + rg * 16 + u;
            __hip_atomic_store(hbuf + oidx, tagbits | (ull)__float_as_uint(h),
                               __ATOMIC_RELAXED, __HIP_MEMORY_SCOPE_AGENT);
            float lp = 0.f;
#pragma unroll
            for (int u2 = 0; u2 < 16; ++u2)
                lp += linl[u][u2] * hnew[bb][u2];
            __hip_atomic_store(lbuf + oidx, tagbits | (ull)__float_as_uint(lp),
                               __ATOMIC_RELAXED, __HIP_MEMORY_SCOPE_AGENT);
        }
        // no trailing barrier: next-step verify self-gates on our publish
    }
}

// ---------------------------------------------------------------------------
extern "C" void kernel_launch(void* const* d_in, const int* in_sizes, int n_in,
                              void* d_out, int out_size, void* d_ws, size_t ws_size,
                              hipStream_t stream)
{
    const float* x     = (const float*)d_in[0];
    const int*   mask  = (const int*)d_in[1];
    const float* Wih_f = (const float*)d_in[2];
    const float* Whh_f = (const float*)d_in[3];
    const float* bih_f = (const float*)d_in[4];
    const float* bhh_f = (const float*)d_in[5];
    const float* Wih_r = (const float*)d_in[6];
    const float* Whh_r = (const float*)d_in[7];
    const float* bih_r = (const float*)d_in[8];
    const float* bhh_r = (const float*)d_in[9];
    const float* fc1_w = (const float*)d_in[10];
    const float* fc2_w = (const float*)d_in[11];
    const float* fc3_w = (const float*)d_in[12];
    const float* fc3_b = (const float*)d_in[13];
    const float* Wih_d = (const float*)d_in[14];
    const float* Whh_d = (const float*)d_in[15];
    const float* bih_d = (const float*)d_in[16];
    const float* bhh_d = (const float*)d_in[17];
    const float* lin_w = (const float*)d_in[18];
    const float* lin_b = (const float*)d_in[19];

    float* ws = (float*)d_ws;
    float* Gf   = ws;
    float* Gr   = ws + 8388608;
    float* hs   = ws + 16777216;
    float* wat  = ws + 25165824;
    float* qp   = ws + 33554432;
    float* kp   = ws + 33718272;
    float* Gd   = ws;
    float* yenc = wat;
    ull* hbuf = (ull*)(wat + 4194304);
    ull* lbuf = hbuf + 16384;

    float* outp = (float*)d_out;
    const int M = NB * TSEQ;       // 16384
    dim3 blk(256);

    // 1-2. encoder input projections (128x64 tiles)
    gemm_nt128<1><<<dim3(M / 128, 8), blk, 0, stream>>>(x, DB, Wih_f, DB, bih_f, bhh_f, Gf, 512, 512, DB);
    gemm_nt128<2><<<dim3(M / 128, 8), blk, 0, stream>>>(x, DB, Wih_r, DB, bih_r, bhh_r, Gr, 512, 512, DB);
    // 3. bidirectional recurrence
    enc_scan<<<dim3(64), dim3(512), 0, stream>>>(Gf, Gr, Whh_f, Whh_r, hs);
    // 4-5. q/k projections (tiny N, 64x64)
    gemm_nt<0><<<dim3(M / 64, 1), blk, 0, stream>>>(hs, 512, fc1_w, 512, nullptr, nullptr, qp, 10, 10, 256);
    gemm_nt<0><<<dim3(M / 64, 1), blk, 0, stream>>>(hs, 512, fc1_w + 256, 512, nullptr, nullptr, kp, 10, 10, 256);
    // 6. attention scores + softmax
    attn_w<<<dim3(M), blk, 0, stream>>>(qp, kp, mask, fc2_w, wat);
    // 7. ctx = w @ hs
    bgemm_nn<<<dim3(8, 4, NB), blk, 0, stream>>>(wat, hs);
    // 8. y_enc (128x64)
    gemm_nt128<0><<<dim3(M / 128, 4), blk, 0, stream>>>(hs, 512, fc3_w, 512, fc3_b, nullptr, yenc, 256, 256, 512);
    // 8.5 decoder comm init
    dec_init4<<<dim3(16), blk, 0, stream>>>(hs, hbuf, lbuf);
    // 9. decoder input projection (128x64)
    gemm_nt128<1><<<dim3(M / 128, 16), blk, 0, stream>>>(yenc, 256, Wih_d, 272, bih_d, bhh_d, Gd, 1024, 1024, 256);
    // 10. decoder recurrence (LDS weights + tag sync)
    dec_scan6<<<dim3(128), blk, 0, stream>>>(Gd, Whh_d, Wih_d, lin_w, lin_b, hbuf, lbuf, outp);
}